// Round 5
// baseline (1699.965 us; speedup 1.0000x reference)
//
#include <hip/hip_runtime.h>

#define NN 50000
#define NE 1600000
#define PER_GRAPH 5000
#define TDIM 10
#define INCH 2
#define D0 12
#define HID 128
#define NBLK 196   // ceil(NN/256)

// ---------------- graph preprocessing ----------------

__global__ void k_init(int* __restrict__ deg, int* __restrict__ fill) {
  int i = blockIdx.x * blockDim.x + threadIdx.x;
  if (i < NN) { deg[i] = 1; fill[i] = 0; }   // deg starts at 1 (self loop)
}

__global__ void k_count(const int* __restrict__ dst, int* __restrict__ deg) {
  int e = blockIdx.x * blockDim.x + threadIdx.x;
  if (e < NE) atomicAdd(&deg[dst[e]], 1);
}

__global__ void k_dinv(const int* __restrict__ deg, float* __restrict__ dinv) {
  int i = blockIdx.x * blockDim.x + threadIdx.x;
  if (i < NN) dinv[i] = rsqrtf((float)deg[i]);   // deg >= 1 always
}

// multi-block exclusive scan of (deg-1): A (per-block scan) -> B (scan of
// block totals) -> C (add offsets). Total is NE by construction.
__global__ __launch_bounds__(256) void k_scanA(const int* __restrict__ deg,
    int* __restrict__ rowptr, int* __restrict__ btot) {
  __shared__ int wsum[4];
  int i = blockIdx.x * 256 + threadIdx.x;
  int lane = threadIdx.x & 63, wid = threadIdx.x >> 6;
  int v = (i < NN) ? deg[i] - 1 : 0;
  int x = v;
  #pragma unroll
  for (int off = 1; off < 64; off <<= 1) {
    int t = __shfl_up(x, off, 64);
    if (lane >= off) x += t;
  }
  if (lane == 63) wsum[wid] = x;
  __syncthreads();
  int wbase = 0;
  for (int w = 0; w < wid; ++w) wbase += wsum[w];
  if (i < NN) rowptr[i] = wbase + x - v;          // block-local exclusive
  if (threadIdx.x == 255) btot[blockIdx.x] = wbase + x;
}

__global__ __launch_bounds__(256) void k_scanB(const int* __restrict__ btot,
    int* __restrict__ boff) {
  __shared__ int wsum[4];
  int tid = threadIdx.x;
  int lane = tid & 63, wid = tid >> 6;
  int v = (tid < NBLK) ? btot[tid] : 0;
  int x = v;
  #pragma unroll
  for (int off = 1; off < 64; off <<= 1) {
    int t = __shfl_up(x, off, 64);
    if (lane >= off) x += t;
  }
  if (lane == 63) wsum[wid] = x;
  __syncthreads();
  int wbase = 0;
  for (int w = 0; w < wid; ++w) wbase += wsum[w];
  if (tid < NBLK) boff[tid] = wbase + x - v;      // exclusive
}

__global__ void k_scanC(const int* __restrict__ boff, int* __restrict__ rowptr) {
  int i = blockIdx.x * 256 + threadIdx.x;
  if (i < NN) rowptr[i] += boff[blockIdx.x];
  if (i == 0) rowptr[NN] = NE;
}

__global__ void k_fill(const int* __restrict__ src, const int* __restrict__ dst,
                       const int* __restrict__ rowptr, int* __restrict__ fill,
                       int* __restrict__ col) {
  int e = blockIdx.x * blockDim.x + threadIdx.x;
  if (e < NE) {
    int d = dst[e];
    int pos = atomicAdd(&fill[d], 1);
    col[rowptr[d] + pos] = src[e];
  }
}

// ---------------- feature construction ----------------

__global__ void k_eps0(const float* __restrict__ x_t, const int* __restrict__ t,
                       const float* __restrict__ t_emb, float* __restrict__ eps0) {
  int idx = blockIdx.x * blockDim.x + threadIdx.x;
  if (idx >= NN * D0) return;
  int i = idx / D0, f = idx - i * D0;
  float v;
  if (f < INCH) v = x_t[i * INCH + f];
  else          v = t_emb[t[i / PER_GRAPH] * TDIM + (f - INCH)];
  eps0[idx] = v;
}

// ---------------- SpMM (Â x) ----------------

// 16-lane group per node (12 active), 4 nodes/wave, unroll x2
__global__ __launch_bounds__(256) void k_spmm12(const float* __restrict__ x,
    const int* __restrict__ rowptr, const int* __restrict__ col,
    const float* __restrict__ dinv, float* __restrict__ xp) {
  int node = blockIdx.x * 16 + (threadIdx.x >> 4);
  if (node >= NN) return;
  int f = threadIdx.x & 15;
  float di = dinv[node];
  float acc = 0.f;
  if (f < D0) acc = di * x[node * D0 + f];
  int p = rowptr[node], pe = rowptr[node + 1];
  for (; p + 2 <= pe; p += 2) {
    int s0 = col[p], s1 = col[p + 1];
    float w0 = dinv[s0], w1 = dinv[s1];
    float u0 = 0.f, u1 = 0.f;
    if (f < D0) { u0 = x[s0 * D0 + f]; u1 = x[s1 * D0 + f]; }
    acc += w0 * u0 + w1 * u1;
  }
  if (p < pe) {
    int s = col[p];
    float w = dinv[s];
    if (f < D0) acc += w * x[s * D0 + f];
  }
  if (f < D0) xp[node * D0 + f] = acc * di;
}

// half-wave (32 lanes, float4) per edge; 2 edges per wave concurrently;
// unroll x8 -> up to 16 independent 512B row loads in flight per wave.
__global__ __launch_bounds__(256) void k_spmm128(const float* __restrict__ x,
    const int* __restrict__ rowptr, const int* __restrict__ col,
    const float* __restrict__ dinv, float* __restrict__ xp) {
  int node = blockIdx.x * 4 + (threadIdx.x >> 6);
  if (node >= NN) return;
  int lane = threadIdx.x & 63;
  int half = lane >> 5;        // 0 or 1
  int l32  = lane & 31;        // float4 chunk index within the 128-float row
  const float4* __restrict__ xr = (const float4*)x;
  float di = dinv[node];
  float4 acc = { 0.f, 0.f, 0.f, 0.f };
  if (!half) {
    float4 v = xr[(size_t)node * 32 + l32];   // self-loop term
    acc.x = di * v.x; acc.y = di * v.y; acc.z = di * v.z; acc.w = di * v.w;
  }
  int beg = rowptr[node], end = rowptr[node + 1];
  int cnt = end - beg;
  int mid = beg + ((cnt + 1) >> 1);
  int p  = half ? mid : beg;
  int pe = half ? end : mid;
  for (; p + 8 <= pe; p += 8) {
    int s0 = col[p],     s1 = col[p + 1], s2 = col[p + 2], s3 = col[p + 3];
    int s4 = col[p + 4], s5 = col[p + 5], s6 = col[p + 6], s7 = col[p + 7];
    float w0 = dinv[s0], w1 = dinv[s1], w2 = dinv[s2], w3 = dinv[s3];
    float w4 = dinv[s4], w5 = dinv[s5], w6 = dinv[s6], w7 = dinv[s7];
    float4 u0 = xr[(size_t)s0 * 32 + l32];
    float4 u1 = xr[(size_t)s1 * 32 + l32];
    float4 u2 = xr[(size_t)s2 * 32 + l32];
    float4 u3 = xr[(size_t)s3 * 32 + l32];
    float4 u4 = xr[(size_t)s4 * 32 + l32];
    float4 u5 = xr[(size_t)s5 * 32 + l32];
    float4 u6 = xr[(size_t)s6 * 32 + l32];
    float4 u7 = xr[(size_t)s7 * 32 + l32];
    acc.x += w0 * u0.x; acc.y += w0 * u0.y; acc.z += w0 * u0.z; acc.w += w0 * u0.w;
    acc.x += w1 * u1.x; acc.y += w1 * u1.y; acc.z += w1 * u1.z; acc.w += w1 * u1.w;
    acc.x += w2 * u2.x; acc.y += w2 * u2.y; acc.z += w2 * u2.z; acc.w += w2 * u2.w;
    acc.x += w3 * u3.x; acc.y += w3 * u3.y; acc.z += w3 * u3.z; acc.w += w3 * u3.w;
    acc.x += w4 * u4.x; acc.y += w4 * u4.y; acc.z += w4 * u4.z; acc.w += w4 * u4.w;
    acc.x += w5 * u5.x; acc.y += w5 * u5.y; acc.z += w5 * u5.z; acc.w += w5 * u5.w;
    acc.x += w6 * u6.x; acc.y += w6 * u6.y; acc.z += w6 * u6.z; acc.w += w6 * u6.w;
    acc.x += w7 * u7.x; acc.y += w7 * u7.y; acc.z += w7 * u7.z; acc.w += w7 * u7.w;
  }
  for (; p + 4 <= pe; p += 4) {
    int s0 = col[p], s1 = col[p + 1], s2 = col[p + 2], s3 = col[p + 3];
    float w0 = dinv[s0], w1 = dinv[s1], w2 = dinv[s2], w3 = dinv[s3];
    float4 u0 = xr[(size_t)s0 * 32 + l32];
    float4 u1 = xr[(size_t)s1 * 32 + l32];
    float4 u2 = xr[(size_t)s2 * 32 + l32];
    float4 u3 = xr[(size_t)s3 * 32 + l32];
    acc.x += w0 * u0.x; acc.y += w0 * u0.y; acc.z += w0 * u0.z; acc.w += w0 * u0.w;
    acc.x += w1 * u1.x; acc.y += w1 * u1.y; acc.z += w1 * u1.z; acc.w += w1 * u1.w;
    acc.x += w2 * u2.x; acc.y += w2 * u2.y; acc.z += w2 * u2.z; acc.w += w2 * u2.w;
    acc.x += w3 * u3.x; acc.y += w3 * u3.y; acc.z += w3 * u3.z; acc.w += w3 * u3.w;
  }
  for (; p < pe; ++p) {
    int s = col[p];
    float w = dinv[s];
    float4 u = xr[(size_t)s * 32 + l32];
    acc.x += w * u.x; acc.y += w * u.y; acc.z += w * u.z; acc.w += w * u.w;
  }
  float4 oth;
  oth.x = __shfl(acc.x, lane ^ 32, 64);
  oth.y = __shfl(acc.y, lane ^ 32, 64);
  oth.z = __shfl(acc.z, lane ^ 32, 64);
  oth.w = __shfl(acc.w, lane ^ 32, 64);
  if (!half) {
    float4 o;
    o.x = (acc.x + oth.x) * di;
    o.y = (acc.y + oth.y) * di;
    o.z = (acc.z + oth.z) * di;
    o.w = (acc.w + oth.w) * di;
    ((float4*)xp)[(size_t)node * 32 + l32] = o;
  }
}

// ---------------- dual GEMM (12 -> 128), 64x128 tile ----------------

template<int KPART, int BK>
__global__ __launch_bounds__(256) void k_gemm(const float* __restrict__ A0,
    const float* __restrict__ A1, const float* __restrict__ W,
    const float* __restrict__ b0, const float* __restrict__ b1,
    float* __restrict__ out) {
  __shared__ __align__(16) float As[BK][64];
  __shared__ __align__(16) float Bs[BK][128];
  int tid = threadIdx.x;
  int tx = tid & 31, ty = tid >> 5;
  int row0 = blockIdx.x * 64;
  float acc[8][4] = {};
  for (int part = 0; part < 2; ++part) {
    const float* A = part ? A1 : A0;
    const float* Wp = W + (size_t)part * KPART * 128;
    for (int k0 = 0; k0 < KPART; k0 += BK) {
      __syncthreads();
      for (int e = tid; e < 64 * BK; e += 256) {
        int m = e / BK, kk = e - m * BK;
        int r = row0 + m;
        As[kk][m] = (r < NN) ? A[(size_t)r * KPART + k0 + kk] : 0.f;
      }
      for (int e2 = tid; e2 < BK * 64; e2 += 256) {
        int kk = e2 >> 6, n2 = (e2 & 63) << 1;
        *(float2*)&Bs[kk][n2] = *(const float2*)&Wp[(size_t)(k0 + kk) * 128 + n2];
      }
      __syncthreads();
      #pragma unroll
      for (int kk = 0; kk < BK; ++kk) {
        float4 a0 = *(const float4*)&As[kk][ty * 8];
        float4 a1 = *(const float4*)&As[kk][ty * 8 + 4];
        float4 bv = *(const float4*)&Bs[kk][tx * 4];
        float am[8] = { a0.x, a0.y, a0.z, a0.w, a1.x, a1.y, a1.z, a1.w };
        #pragma unroll
        for (int i = 0; i < 8; ++i) {
          acc[i][0] += am[i] * bv.x;
          acc[i][1] += am[i] * bv.y;
          acc[i][2] += am[i] * bv.z;
          acc[i][3] += am[i] * bv.w;
        }
      }
    }
  }
  float bx = b0[tx * 4 + 0] + b1[tx * 4 + 0];
  float by = b0[tx * 4 + 1] + b1[tx * 4 + 1];
  float bz = b0[tx * 4 + 2] + b1[tx * 4 + 2];
  float bw = b0[tx * 4 + 3] + b1[tx * 4 + 3];
  #pragma unroll
  for (int i = 0; i < 8; ++i) {
    int r = row0 + ty * 8 + i;
    if (r < NN) {
      float4 o;
      o.x = fmaxf(acc[i][0] + bx, 0.f);
      o.y = fmaxf(acc[i][1] + by, 0.f);
      o.z = fmaxf(acc[i][2] + bz, 0.f);
      o.w = fmaxf(acc[i][3] + bw, 0.f);
      *(float4*)&out[(size_t)r * 128 + tx * 4] = o;
    }
  }
}

// ---------------- split-part GEMM (128 -> 128): blockIdx.y selects part ----
// Writes RAW partials (no bias/relu); k_epi fuses them.

__global__ __launch_bounds__(256) void k_gemmK(const float* __restrict__ A0,
    const float* __restrict__ A1, const float* __restrict__ W,
    float* __restrict__ out0, float* __restrict__ out1) {
  constexpr int BK = 16;
  __shared__ __align__(16) float As[BK][128];
  __shared__ __align__(16) float Bs[BK][128];
  int part = blockIdx.y;
  const float* __restrict__ A  = part ? A1 : A0;
  const float* __restrict__ Wp = W + (size_t)part * 128 * 128;
  float* __restrict__ out = part ? out1 : out0;
  int tid = threadIdx.x;
  int tx = tid & 15;           // cols tx*4..+3 and 64+tx*4..+3
  int ty = tid >> 4;           // 16 row groups of 8
  int row0 = blockIdx.x * 128;
  float acc[8][8] = {};
  int lm = tid >> 1;           // A-load row 0..127
  int lk = (tid & 1) * 8;      // A-load k offset 0 or 8

  for (int k0 = 0; k0 < 128; k0 += BK) {
    __syncthreads();
    {
      int r = row0 + lm;
      float4 v0 = { 0, 0, 0, 0 }, v1 = { 0, 0, 0, 0 };
      if (r < NN) {
        v0 = *(const float4*)&A[(size_t)r * 128 + k0 + lk];
        v1 = *(const float4*)&A[(size_t)r * 128 + k0 + lk + 4];
      }
      As[lk + 0][lm] = v0.x; As[lk + 1][lm] = v0.y;
      As[lk + 2][lm] = v0.z; As[lk + 3][lm] = v0.w;
      As[lk + 4][lm] = v1.x; As[lk + 5][lm] = v1.y;
      As[lk + 6][lm] = v1.z; As[lk + 7][lm] = v1.w;
    }
    {
      int i0 = tid;
      int kk = i0 >> 5, n4 = (i0 & 31) << 2;
      *(float4*)&Bs[kk][n4] = *(const float4*)&Wp[(size_t)(k0 + kk) * 128 + n4];
      int i1 = tid + 256;
      kk = i1 >> 5; n4 = (i1 & 31) << 2;
      *(float4*)&Bs[kk][n4] = *(const float4*)&Wp[(size_t)(k0 + kk) * 128 + n4];
    }
    __syncthreads();
    #pragma unroll
    for (int kk = 0; kk < BK; ++kk) {
      float4 a0 = *(const float4*)&As[kk][ty * 8];
      float4 a1 = *(const float4*)&As[kk][ty * 8 + 4];
      float4 bv0 = *(const float4*)&Bs[kk][tx * 4];
      float4 bv1 = *(const float4*)&Bs[kk][64 + tx * 4];
      float am[8] = { a0.x, a0.y, a0.z, a0.w, a1.x, a1.y, a1.z, a1.w };
      float bn[8] = { bv0.x, bv0.y, bv0.z, bv0.w, bv1.x, bv1.y, bv1.z, bv1.w };
      #pragma unroll
      for (int i = 0; i < 8; ++i)
        #pragma unroll
        for (int j = 0; j < 8; ++j)
          acc[i][j] += am[i] * bn[j];
    }
  }
  #pragma unroll
  for (int i = 0; i < 8; ++i) {
    int r = row0 + ty * 8 + i;
    if (r < NN) {
      float4 o0 = { acc[i][0], acc[i][1], acc[i][2], acc[i][3] };
      float4 o1 = { acc[i][4], acc[i][5], acc[i][6], acc[i][7] };
      *(float4*)&out[(size_t)r * 128 + tx * 4] = o0;
      *(float4*)&out[(size_t)r * 128 + 64 + tx * 4] = o1;
    }
  }
}

// epilogue: h = relu(h + p1 + b0 + b1), elementwise float4
__global__ __launch_bounds__(256) void k_epi(float* __restrict__ h,
    const float* __restrict__ p1, const float* __restrict__ b0,
    const float* __restrict__ b1) {
  int idx = blockIdx.x * blockDim.x + threadIdx.x;   // float4 index
  if (idx >= NN * 32) return;
  int c4 = (idx & 31) << 2;                          // starting col of this float4
  float4 a = ((const float4*)h)[idx];
  float4 b = ((const float4*)p1)[idx];
  float4 o;
  o.x = fmaxf(a.x + b.x + b0[c4 + 0] + b1[c4 + 0], 0.f);
  o.y = fmaxf(a.y + b.y + b0[c4 + 1] + b1[c4 + 1], 0.f);
  o.z = fmaxf(a.z + b.z + b0[c4 + 2] + b1[c4 + 2], 0.f);
  o.w = fmaxf(a.w + b.w + b0[c4 + 3] + b1[c4 + 3], 0.f);
  ((float4*)h)[idx] = o;
}

// ---------------- output layer (N=2) ----------------

__global__ __launch_bounds__(256) void k_out(const float* __restrict__ h,
    const float* __restrict__ xp, const float* __restrict__ Wo,
    const float* __restrict__ bo, float* __restrict__ out) {
  int node = blockIdx.x * 4 + (threadIdx.x >> 6);
  if (node >= NN) return;
  int lane = threadIdx.x & 63;
  float a0 = 0.f, a1 = 0.f;
  #pragma unroll
  for (int tph = 0; tph < 2; ++tph) {
    int k = lane + tph * 64;
    float hv = h[(size_t)node * HID + k];
    float xv = xp[(size_t)node * HID + k];
    a0 += hv * Wo[k * 2 + 0] + xv * Wo[256 + k * 2 + 0];
    a1 += hv * Wo[k * 2 + 1] + xv * Wo[256 + k * 2 + 1];
  }
  #pragma unroll
  for (int off = 32; off; off >>= 1) {
    a0 += __shfl_down(a0, off, 64);
    a1 += __shfl_down(a1, off, 64);
  }
  if (lane == 0) {
    out[node * 2 + 0] = fmaxf(a0 + bo[0] + bo[2], 0.f);
    out[node * 2 + 1] = fmaxf(a1 + bo[1] + bo[3], 0.f);
  }
}

// ---------------- launcher ----------------

extern "C" void kernel_launch(void* const* d_in, const int* in_sizes, int n_in,
                              void* d_out, int out_size, void* d_ws, size_t ws_size,
                              hipStream_t stream) {
  const float* x_t   = (const float*)d_in[0];
  const int*   eidx  = (const int*)d_in[1];
  const int*   t     = (const int*)d_in[2];
  const float* t_emb = (const float*)d_in[3];
  const float* W_in  = (const float*)d_in[4];
  const float* b_in  = (const float*)d_in[5];
  const float* W_hid = (const float*)d_in[6];
  const float* b_hid = (const float*)d_in[7];
  const float* W_out = (const float*)d_in[8];
  const float* b_out = (const float*)d_in[9];
  float* out = (float*)d_out;

  char* ws = (char*)d_ws;
  size_t off = 0;
  auto take = [&](size_t bytes) {
    char* p = ws + off;
    off += (bytes + 255) & ~(size_t)255;
    return p;
  };
  int*   deg    = (int*)take((size_t)NN * 4);
  int*   fill   = (int*)take((size_t)NN * 4);
  int*   rowptr = (int*)take((size_t)(NN + 1) * 4);
  int*   btot   = (int*)take((size_t)NBLK * 4);
  int*   boff   = (int*)take((size_t)NBLK * 4);
  float* dinv   = (float*)take((size_t)NN * 4);
  int*   col    = (int*)take((size_t)NE * 4);
  float* eps0   = (float*)take((size_t)NN * D0 * 4);
  float* xp0    = (float*)take((size_t)NN * D0 * 4);
  float* h0     = (float*)take((size_t)NN * HID * 4);
  float* h1     = (float*)take((size_t)NN * HID * 4);
  float* xp     = (float*)take((size_t)NN * HID * 4);
  float* p1buf  = (float*)take((size_t)NN * HID * 4);

  const int* src = eidx;
  const int* dst = eidx + NE;

  hipLaunchKernelGGL(k_init,  dim3((NN + 255) / 256), dim3(256), 0, stream, deg, fill);
  hipLaunchKernelGGL(k_count, dim3((NE + 255) / 256), dim3(256), 0, stream, dst, deg);
  hipLaunchKernelGGL(k_dinv,  dim3((NN + 255) / 256), dim3(256), 0, stream, deg, dinv);
  hipLaunchKernelGGL(k_scanA, dim3(NBLK), dim3(256), 0, stream, deg, rowptr, btot);
  hipLaunchKernelGGL(k_scanB, dim3(1), dim3(256), 0, stream, btot, boff);
  hipLaunchKernelGGL(k_scanC, dim3(NBLK), dim3(256), 0, stream, boff, rowptr);
  hipLaunchKernelGGL(k_fill,  dim3((NE + 255) / 256), dim3(256), 0, stream, src, dst, rowptr, fill, col);
  hipLaunchKernelGGL(k_eps0,  dim3((NN * D0 + 255) / 256), dim3(256), 0, stream, x_t, t, t_emb, eps0);

  // layer 1: 12 -> 128 (fused bias+relu in k_gemm)
  hipLaunchKernelGGL(k_spmm12, dim3((NN + 15) / 16), dim3(256), 0, stream, eps0, rowptr, col, dinv, xp0);
  hipLaunchKernelGGL((k_gemm<12, 12>), dim3((NN + 63) / 64), dim3(256), 0, stream,
                     eps0, xp0, W_in, b_in, b_in + 128, h0);

  // 7 hidden layers: 128 -> 128 (split-part GEMM + epilogue)
  float* cur = h0;
  float* nxt = h1;
  for (int i = 0; i < 7; ++i) {
    const float* Wl = W_hid + (size_t)i * 2 * 128 * 128;
    const float* bl = b_hid + (size_t)i * 2 * 128;
    hipLaunchKernelGGL(k_spmm128, dim3((NN + 3) / 4), dim3(256), 0, stream, cur, rowptr, col, dinv, xp);
    hipLaunchKernelGGL(k_gemmK, dim3((NN + 127) / 128, 2), dim3(256), 0, stream,
                       cur, xp, Wl, nxt, p1buf);
    hipLaunchKernelGGL(k_epi, dim3((NN * 32 + 255) / 256), dim3(256), 0, stream,
                       nxt, p1buf, bl, bl + 128);
    float* tmp = cur; cur = nxt; nxt = tmp;
  }

  // output layer: 128 -> 2
  hipLaunchKernelGGL(k_spmm128, dim3((NN + 3) / 4), dim3(256), 0, stream, cur, rowptr, col, dinv, xp);
  hipLaunchKernelGGL(k_out, dim3((NN + 3) / 4), dim3(256), 0, stream, cur, xp, W_out, b_out, out);
}

// Round 6
// 939.586 us; speedup vs baseline: 1.8093x; 1.8093x over previous
//
#include <hip/hip_runtime.h>

#define NN 50000
#define NE 1600000
#define PER_GRAPH 5000
#define TDIM 10
#define INCH 2
#define D0 12
#define HID 128
#define NBLK 196   // ceil(NN/256)
#define NHID 7

typedef short s16x8 __attribute__((ext_vector_type(8)));
typedef float f32x4 __attribute__((ext_vector_type(4)));
typedef _Float16 f16x4 __attribute__((ext_vector_type(4)));

__device__ inline unsigned short bf16h(float v) {
  unsigned u = __float_as_uint(v);
  return (unsigned short)((u + 0x7FFFu + ((u >> 16) & 1u)) >> 16);
}
__device__ inline float bf16tof(unsigned short h) {
  return __uint_as_float((unsigned)h << 16);
}
__device__ inline s16x8 zero8() {
  s16x8 z;
  #pragma unroll
  for (int i = 0; i < 8; ++i) z[i] = 0;
  return z;
}

// ---------------- graph preprocessing ----------------

__global__ void k_init(int* __restrict__ deg, int* __restrict__ fill) {
  int i = blockIdx.x * blockDim.x + threadIdx.x;
  if (i < NN) { deg[i] = 1; fill[i] = 0; }
}

__global__ void k_count(const int* __restrict__ dst, int* __restrict__ deg) {
  int e = blockIdx.x * blockDim.x + threadIdx.x;
  if (e < NE) atomicAdd(&deg[dst[e]], 1);
}

__global__ void k_dinv(const int* __restrict__ deg, float* __restrict__ dinv) {
  int i = blockIdx.x * blockDim.x + threadIdx.x;
  if (i < NN) dinv[i] = rsqrtf((float)deg[i]);
}

__global__ __launch_bounds__(256) void k_scanA(const int* __restrict__ deg,
    int* __restrict__ rowptr, int* __restrict__ btot) {
  __shared__ int wsum[4];
  int i = blockIdx.x * 256 + threadIdx.x;
  int lane = threadIdx.x & 63, wid = threadIdx.x >> 6;
  int v = (i < NN) ? deg[i] - 1 : 0;
  int x = v;
  #pragma unroll
  for (int off = 1; off < 64; off <<= 1) {
    int t = __shfl_up(x, off, 64);
    if (lane >= off) x += t;
  }
  if (lane == 63) wsum[wid] = x;
  __syncthreads();
  int wbase = 0;
  for (int w = 0; w < wid; ++w) wbase += wsum[w];
  if (i < NN) rowptr[i] = wbase + x - v;
  if (threadIdx.x == 255) btot[blockIdx.x] = wbase + x;
}

__global__ __launch_bounds__(256) void k_scanB(const int* __restrict__ btot,
    int* __restrict__ boff) {
  __shared__ int wsum[4];
  int tid = threadIdx.x;
  int lane = tid & 63, wid = tid >> 6;
  int v = (tid < NBLK) ? btot[tid] : 0;
  int x = v;
  #pragma unroll
  for (int off = 1; off < 64; off <<= 1) {
    int t = __shfl_up(x, off, 64);
    if (lane >= off) x += t;
  }
  if (lane == 63) wsum[wid] = x;
  __syncthreads();
  int wbase = 0;
  for (int w = 0; w < wid; ++w) wbase += wsum[w];
  if (tid < NBLK) boff[tid] = wbase + x - v;
}

__global__ void k_scanC(const int* __restrict__ boff, int* __restrict__ rowptr) {
  int i = blockIdx.x * 256 + threadIdx.x;
  if (i < NN) rowptr[i] += boff[blockIdx.x];
  if (i == 0) rowptr[NN] = NE;
}

__global__ void k_fill(const int* __restrict__ src, const int* __restrict__ dst,
                       const int* __restrict__ rowptr, int* __restrict__ fill,
                       int* __restrict__ col) {
  int e = blockIdx.x * blockDim.x + threadIdx.x;
  if (e < NE) {
    int d = dst[e];
    int pos = atomicAdd(&fill[d], 1);
    col[rowptr[d] + pos] = src[e];
  }
}

// ---------------- feature construction ----------------

__global__ void k_eps0(const float* __restrict__ x_t, const int* __restrict__ t,
                       const float* __restrict__ t_emb, float* __restrict__ eps0) {
  int idx = blockIdx.x * blockDim.x + threadIdx.x;
  if (idx >= NN * D0) return;
  int i = idx / D0, f = idx - i * D0;
  float v;
  if (f < INCH) v = x_t[i * INCH + f];
  else          v = t_emb[t[i / PER_GRAPH] * TDIM + (f - INCH)];
  eps0[idx] = v;
}

// weight split: W_hid (7,2,128k,128n) fp32 -> transposed bf16 hi/lo [7][2][n][k]
__global__ void k_splitW(const float* __restrict__ W, unsigned short* __restrict__ WhiT,
                         unsigned short* __restrict__ WloT) {
  int idx = blockIdx.x * blockDim.x + threadIdx.x;
  if (idx >= NHID * 2 * 128 * 128) return;
  int pl = idx >> 14;
  int e = idx & 16383;
  int k = e >> 7, n = e & 127;
  float v = W[idx];
  unsigned short h = bf16h(v);
  int o = (pl << 14) + (n << 7) + k;
  WhiT[o] = h;
  WloT[o] = bf16h(v - bf16tof(h));
}

// ---------------- SpMM (Â x) ----------------

__global__ __launch_bounds__(256) void k_spmm12(const float* __restrict__ x,
    const int* __restrict__ rowptr, const int* __restrict__ col,
    const float* __restrict__ dinv, float* __restrict__ xp) {
  int node = blockIdx.x * 16 + (threadIdx.x >> 4);
  if (node >= NN) return;
  int f = threadIdx.x & 15;
  float di = dinv[node];
  float acc = 0.f;
  if (f < D0) acc = di * x[node * D0 + f];
  int p = rowptr[node], pe = rowptr[node + 1];
  for (; p + 2 <= pe; p += 2) {
    int s0 = col[p], s1 = col[p + 1];
    float w0 = dinv[s0], w1 = dinv[s1];
    float u0 = 0.f, u1 = 0.f;
    if (f < D0) { u0 = x[s0 * D0 + f]; u1 = x[s1 * D0 + f]; }
    acc += w0 * u0 + w1 * u1;
  }
  if (p < pe) {
    int s = col[p];
    float w = dinv[s];
    if (f < D0) acc += w * x[s * D0 + f];
  }
  if (f < D0) xp[node * D0 + f] = acc * di;
}

// f16 gather (256B/row); accumulate fp32; write xp as bf16 hi/lo pair.
__global__ __launch_bounds__(256) void k_spmm128(const _Float16* __restrict__ x,
    const int* __restrict__ rowptr, const int* __restrict__ col,
    const float* __restrict__ dinv, unsigned short* __restrict__ xphi,
    unsigned short* __restrict__ xplo) {
  int node = blockIdx.x * 4 + (threadIdx.x >> 6);
  if (node >= NN) return;
  int lane = threadIdx.x & 63;
  int half = lane >> 5;
  int l32  = lane & 31;                 // 4-f16 chunk index in the 128-wide row
  const f16x4* __restrict__ xr = (const f16x4*)x;
  float di = dinv[node];
  float a0 = 0.f, a1 = 0.f, a2 = 0.f, a3 = 0.f;
  if (!half) {
    f16x4 v = xr[(size_t)node * 32 + l32];
    a0 = di * (float)v.x; a1 = di * (float)v.y;
    a2 = di * (float)v.z; a3 = di * (float)v.w;
  }
  int beg = rowptr[node], end = rowptr[node + 1];
  int cnt = end - beg;
  int mid = beg + ((cnt + 1) >> 1);
  int p  = half ? mid : beg;
  int pe = half ? end : mid;
  for (; p + 4 <= pe; p += 4) {
    int s0 = col[p], s1 = col[p + 1], s2 = col[p + 2], s3 = col[p + 3];
    float w0 = dinv[s0], w1 = dinv[s1], w2 = dinv[s2], w3 = dinv[s3];
    f16x4 u0 = xr[(size_t)s0 * 32 + l32];
    f16x4 u1 = xr[(size_t)s1 * 32 + l32];
    f16x4 u2 = xr[(size_t)s2 * 32 + l32];
    f16x4 u3 = xr[(size_t)s3 * 32 + l32];
    a0 += w0 * (float)u0.x; a1 += w0 * (float)u0.y; a2 += w0 * (float)u0.z; a3 += w0 * (float)u0.w;
    a0 += w1 * (float)u1.x; a1 += w1 * (float)u1.y; a2 += w1 * (float)u1.z; a3 += w1 * (float)u1.w;
    a0 += w2 * (float)u2.x; a1 += w2 * (float)u2.y; a2 += w2 * (float)u2.z; a3 += w2 * (float)u2.w;
    a0 += w3 * (float)u3.x; a1 += w3 * (float)u3.y; a2 += w3 * (float)u3.z; a3 += w3 * (float)u3.w;
  }
  for (; p < pe; ++p) {
    int s = col[p];
    float w = dinv[s];
    f16x4 u = xr[(size_t)s * 32 + l32];
    a0 += w * (float)u.x; a1 += w * (float)u.y; a2 += w * (float)u.z; a3 += w * (float)u.w;
  }
  float o0 = a0 + __shfl(a0, lane ^ 32, 64);
  float o1 = a1 + __shfl(a1, lane ^ 32, 64);
  float o2 = a2 + __shfl(a2, lane ^ 32, 64);
  float o3 = a3 + __shfl(a3, lane ^ 32, 64);
  if (!half) {
    o0 *= di; o1 *= di; o2 *= di; o3 *= di;
    ushort4 h, l;
    h.x = bf16h(o0); l.x = bf16h(o0 - bf16tof(h.x));
    h.y = bf16h(o1); l.y = bf16h(o1 - bf16tof(h.y));
    h.z = bf16h(o2); l.z = bf16h(o2 - bf16tof(h.z));
    h.w = bf16h(o3); l.w = bf16h(o3 - bf16tof(h.w));
    *(ushort4*)&xphi[(size_t)node * 128 + l32 * 4] = h;
    *(ushort4*)&xplo[(size_t)node * 128 + l32 * 4] = l;
  }
}

// ---------------- layer-1 GEMM (12 -> 128), fp32 VALU, split outputs -------

__global__ __launch_bounds__(256) void k_gemm12(const float* __restrict__ A0,
    const float* __restrict__ A1, const float* __restrict__ W,
    const float* __restrict__ b0, const float* __restrict__ b1,
    _Float16* __restrict__ hf, unsigned short* __restrict__ hbhi,
    unsigned short* __restrict__ hblo) {
  constexpr int BK = D0;
  __shared__ __align__(16) float As[BK][64];
  __shared__ __align__(16) float Bs[BK][128];
  int tid = threadIdx.x;
  int tx = tid & 31, ty = tid >> 5;
  int row0 = blockIdx.x * 64;
  float acc[8][4] = {};
  for (int part = 0; part < 2; ++part) {
    const float* A = part ? A1 : A0;
    const float* Wp = W + (size_t)part * D0 * 128;
    __syncthreads();
    for (int e = tid; e < 64 * BK; e += 256) {
      int m = e / BK, kk = e - m * BK;
      int r = row0 + m;
      As[kk][m] = (r < NN) ? A[(size_t)r * D0 + kk] : 0.f;
    }
    for (int e2 = tid; e2 < BK * 64; e2 += 256) {
      int kk = e2 >> 6, n2 = (e2 & 63) << 1;
      *(float2*)&Bs[kk][n2] = *(const float2*)&Wp[(size_t)kk * 128 + n2];
    }
    __syncthreads();
    #pragma unroll
    for (int kk = 0; kk < BK; ++kk) {
      float4 a0 = *(const float4*)&As[kk][ty * 8];
      float4 a1 = *(const float4*)&As[kk][ty * 8 + 4];
      float4 bv = *(const float4*)&Bs[kk][tx * 4];
      float am[8] = { a0.x, a0.y, a0.z, a0.w, a1.x, a1.y, a1.z, a1.w };
      #pragma unroll
      for (int i = 0; i < 8; ++i) {
        acc[i][0] += am[i] * bv.x;
        acc[i][1] += am[i] * bv.y;
        acc[i][2] += am[i] * bv.z;
        acc[i][3] += am[i] * bv.w;
      }
    }
  }
  float bb[4];
  #pragma unroll
  for (int j = 0; j < 4; ++j) bb[j] = b0[tx * 4 + j] + b1[tx * 4 + j];
  #pragma unroll
  for (int i = 0; i < 8; ++i) {
    int r = row0 + ty * 8 + i;
    if (r < NN) {
      float v[4];
      #pragma unroll
      for (int j = 0; j < 4; ++j) v[j] = fmaxf(acc[i][j] + bb[j], 0.f);
      f16x4 hv; ushort4 hh, hl;
      #pragma unroll
      for (int j = 0; j < 4; ++j) {
        hv[j] = (_Float16)v[j];
        unsigned short h = bf16h(v[j]);
        ((unsigned short*)&hh)[j] = h;
        ((unsigned short*)&hl)[j] = bf16h(v[j] - bf16tof(h));
      }
      *(f16x4*)&hf[(size_t)r * 128 + tx * 4] = hv;
      *(ushort4*)&hbhi[(size_t)r * 128 + tx * 4] = hh;
      *(ushort4*)&hblo[(size_t)r * 128 + tx * 4] = hl;
    }
  }
}

// ---------------- hidden GEMM: bf16x2-split MFMA, 64x128 tile, fused epi ---
// out = relu(A@[W0;W1] + b0 + b1), A = [h | xp] (bf16 hi/lo pairs), K=256.

__global__ __launch_bounds__(256) void k_gemmM(
    const unsigned short* __restrict__ Ahi0, const unsigned short* __restrict__ Alo0,
    const unsigned short* __restrict__ Ahi1, const unsigned short* __restrict__ Alo1,
    const unsigned short* __restrict__ WhiT, const unsigned short* __restrict__ WloT,
    const float* __restrict__ b0, const float* __restrict__ b1,
    _Float16* __restrict__ hf, unsigned short* __restrict__ hbhi,
    unsigned short* __restrict__ hblo) {
  __shared__ __align__(16) unsigned short AsH[64 * 32], AsL[64 * 32];
  __shared__ __align__(16) unsigned short BsH[128 * 32], BsL[128 * 32];
  int tid = threadIdx.x;
  int lane = tid & 63, w = tid >> 6;
  int row0 = blockIdx.x * 64;
  int lrow = lane & 15, kc = lane >> 4;
  int slotR = kc ^ ((lrow >> 1) & 3);

  f32x4 acc[4][2];
  #pragma unroll
  for (int mi = 0; mi < 4; ++mi)
    #pragma unroll
    for (int ni = 0; ni < 2; ++ni)
      #pragma unroll
      for (int j = 0; j < 4; ++j) acc[mi][ni][j] = 0.f;

  int ar = tid >> 2, ac4 = tid & 3;   // A staging: row 0..63, k-chunk 0..3
  int slA = ac4 ^ ((ar >> 1) & 3);

  for (int part = 0; part < 2; ++part) {
    const unsigned short* __restrict__ Ah = part ? Ahi1 : Ahi0;
    const unsigned short* __restrict__ Al = part ? Alo1 : Alo0;
    const unsigned short* __restrict__ Bh = WhiT + (part << 14);
    const unsigned short* __restrict__ Bl = WloT + (part << 14);
    for (int k0 = 0; k0 < 128; k0 += 32) {
      __syncthreads();
      {
        int gr = row0 + ar;
        s16x8 vh = zero8(), vl = zero8();
        if (gr < NN) {
          vh = *(const s16x8*)&Ah[(size_t)gr * 128 + k0 + ac4 * 8];
          vl = *(const s16x8*)&Al[(size_t)gr * 128 + k0 + ac4 * 8];
        }
        *(s16x8*)&AsH[ar * 32 + slA * 8] = vh;
        *(s16x8*)&AsL[ar * 32 + slA * 8] = vl;
      }
      #pragma unroll
      for (int j = 0; j < 2; ++j) {
        int idx = tid + j * 256;        // 0..511
        int bcol = idx >> 2, c4 = idx & 3;
        int slB = c4 ^ ((bcol >> 1) & 3);
        *(s16x8*)&BsH[bcol * 32 + slB * 8] = *(const s16x8*)&Bh[bcol * 128 + k0 + c4 * 8];
        *(s16x8*)&BsL[bcol * 32 + slB * 8] = *(const s16x8*)&Bl[bcol * 128 + k0 + c4 * 8];
      }
      __syncthreads();
      s16x8 aH[4], aL[4], bH[2], bL[2];
      #pragma unroll
      for (int mi = 0; mi < 4; ++mi) {
        int r = mi * 16 + lrow;
        aH[mi] = *(const s16x8*)&AsH[r * 32 + slotR * 8];
        aL[mi] = *(const s16x8*)&AsL[r * 32 + slotR * 8];
      }
      #pragma unroll
      for (int ni = 0; ni < 2; ++ni) {
        int c = w * 32 + ni * 16 + lrow;
        bH[ni] = *(const s16x8*)&BsH[c * 32 + slotR * 8];
        bL[ni] = *(const s16x8*)&BsL[c * 32 + slotR * 8];
      }
      #pragma unroll
      for (int mi = 0; mi < 4; ++mi)
        #pragma unroll
        for (int ni = 0; ni < 2; ++ni) {
          acc[mi][ni] = __builtin_amdgcn_mfma_f32_16x16x32_bf16(aH[mi], bH[ni], acc[mi][ni], 0, 0, 0);
          acc[mi][ni] = __builtin_amdgcn_mfma_f32_16x16x32_bf16(aH[mi], bL[ni], acc[mi][ni], 0, 0, 0);
          acc[mi][ni] = __builtin_amdgcn_mfma_f32_16x16x32_bf16(aL[mi], bH[ni], acc[mi][ni], 0, 0, 0);
        }
    }
  }
  // epilogue: D layout col = lane&15, row = (lane>>4)*4 + reg  (+16*mi, +offsets)
  #pragma unroll
  for (int ni = 0; ni < 2; ++ni) {
    int c = w * 32 + ni * 16 + lrow;
    float bias = b0[c] + b1[c];
    #pragma unroll
    for (int mi = 0; mi < 4; ++mi) {
      #pragma unroll
      for (int reg = 0; reg < 4; ++reg) {
        int r = row0 + mi * 16 + kc * 4 + reg;
        if (r < NN) {
          float v = fmaxf(acc[mi][ni][reg] + bias, 0.f);
          hf[(size_t)r * 128 + c] = (_Float16)v;
          unsigned short h = bf16h(v);
          hbhi[(size_t)r * 128 + c] = h;
          hblo[(size_t)r * 128 + c] = bf16h(v - bf16tof(h));
        }
      }
    }
  }
}

// ---------------- output layer (N=2) ----------------

__global__ __launch_bounds__(256) void k_out(const _Float16* __restrict__ hf,
    const unsigned short* __restrict__ xphi, const unsigned short* __restrict__ xplo,
    const float* __restrict__ Wo, const float* __restrict__ bo,
    float* __restrict__ out) {
  int node = blockIdx.x * 4 + (threadIdx.x >> 6);
  if (node >= NN) return;
  int lane = threadIdx.x & 63;
  float a0 = 0.f, a1 = 0.f;
  #pragma unroll
  for (int tph = 0; tph < 2; ++tph) {
    int k = lane + tph * 64;
    float hv = (float)hf[(size_t)node * HID + k];
    float xv = bf16tof(xphi[(size_t)node * HID + k]) + bf16tof(xplo[(size_t)node * HID + k]);
    a0 += hv * Wo[k * 2 + 0] + xv * Wo[256 + k * 2 + 0];
    a1 += hv * Wo[k * 2 + 1] + xv * Wo[256 + k * 2 + 1];
  }
  #pragma unroll
  for (int off = 32; off; off >>= 1) {
    a0 += __shfl_down(a0, off, 64);
    a1 += __shfl_down(a1, off, 64);
  }
  if (lane == 0) {
    out[node * 2 + 0] = fmaxf(a0 + bo[0] + bo[2], 0.f);
    out[node * 2 + 1] = fmaxf(a1 + bo[1] + bo[3], 0.f);
  }
}

// ---------------- launcher ----------------

extern "C" void kernel_launch(void* const* d_in, const int* in_sizes, int n_in,
                              void* d_out, int out_size, void* d_ws, size_t ws_size,
                              hipStream_t stream) {
  const float* x_t   = (const float*)d_in[0];
  const int*   eidx  = (const int*)d_in[1];
  const int*   t     = (const int*)d_in[2];
  const float* t_emb = (const float*)d_in[3];
  const float* W_in  = (const float*)d_in[4];
  const float* b_in  = (const float*)d_in[5];
  const float* W_hid = (const float*)d_in[6];
  const float* b_hid = (const float*)d_in[7];
  const float* W_out = (const float*)d_in[8];
  const float* b_out = (const float*)d_in[9];
  float* out = (float*)d_out;

  char* ws = (char*)d_ws;
  size_t off = 0;
  auto take = [&](size_t bytes) {
    char* p = ws + off;
    off += (bytes + 255) & ~(size_t)255;
    return p;
  };
  int*   deg    = (int*)take((size_t)NN * 4);
  int*   fill   = (int*)take((size_t)NN * 4);
  int*   rowptr = (int*)take((size_t)(NN + 1) * 4);
  int*   btot   = (int*)take((size_t)NBLK * 4);
  int*   boff   = (int*)take((size_t)NBLK * 4);
  float* dinv   = (float*)take((size_t)NN * 4);
  int*   col    = (int*)take((size_t)NE * 4);
  float* eps0   = (float*)take((size_t)NN * D0 * 4);
  float* xp0    = (float*)take((size_t)NN * D0 * 4);
  _Float16* hf0 = (_Float16*)take((size_t)NN * HID * 2);
  _Float16* hf1 = (_Float16*)take((size_t)NN * HID * 2);
  unsigned short* hbhi0 = (unsigned short*)take((size_t)NN * HID * 2);
  unsigned short* hbhi1 = (unsigned short*)take((size_t)NN * HID * 2);
  unsigned short* hblo0 = (unsigned short*)take((size_t)NN * HID * 2);
  unsigned short* hblo1 = (unsigned short*)take((size_t)NN * HID * 2);
  unsigned short* xphi  = (unsigned short*)take((size_t)NN * HID * 2);
  unsigned short* xplo  = (unsigned short*)take((size_t)NN * HID * 2);
  unsigned short* WhiT  = (unsigned short*)take((size_t)NHID * 2 * 128 * 128 * 2);
  unsigned short* WloT  = (unsigned short*)take((size_t)NHID * 2 * 128 * 128 * 2);

  const int* src = eidx;
  const int* dst = eidx + NE;

  hipLaunchKernelGGL(k_init,   dim3((NN + 255) / 256), dim3(256), 0, stream, deg, fill);
  hipLaunchKernelGGL(k_count,  dim3((NE + 255) / 256), dim3(256), 0, stream, dst, deg);
  hipLaunchKernelGGL(k_dinv,   dim3((NN + 255) / 256), dim3(256), 0, stream, deg, dinv);
  hipLaunchKernelGGL(k_scanA,  dim3(NBLK), dim3(256), 0, stream, deg, rowptr, btot);
  hipLaunchKernelGGL(k_scanB,  dim3(1), dim3(256), 0, stream, btot, boff);
  hipLaunchKernelGGL(k_scanC,  dim3(NBLK), dim3(256), 0, stream, boff, rowptr);
  hipLaunchKernelGGL(k_fill,   dim3((NE + 255) / 256), dim3(256), 0, stream, src, dst, rowptr, fill, col);
  hipLaunchKernelGGL(k_eps0,   dim3((NN * D0 + 255) / 256), dim3(256), 0, stream, x_t, t, t_emb, eps0);
  hipLaunchKernelGGL(k_splitW, dim3((NHID * 2 * 128 * 128 + 255) / 256), dim3(256), 0, stream,
                     W_hid, WhiT, WloT);

  // layer 1: 12 -> 128 (fp32 VALU GEMM, split outputs)
  hipLaunchKernelGGL(k_spmm12, dim3((NN + 15) / 16), dim3(256), 0, stream, eps0, rowptr, col, dinv, xp0);
  hipLaunchKernelGGL(k_gemm12, dim3((NN + 63) / 64), dim3(256), 0, stream,
                     eps0, xp0, W_in, b_in, b_in + 128, hf0, hbhi0, hblo0);

  // 7 hidden layers
  _Float16* hfC = hf0;  _Float16* hfN = hf1;
  unsigned short* hhiC = hbhi0; unsigned short* hhiN = hbhi1;
  unsigned short* hloC = hblo0; unsigned short* hloN = hblo1;
  for (int i = 0; i < NHID; ++i) {
    hipLaunchKernelGGL(k_spmm128, dim3((NN + 3) / 4), dim3(256), 0, stream,
                       hfC, rowptr, col, dinv, xphi, xplo);
    hipLaunchKernelGGL(k_gemmM, dim3((NN + 63) / 64), dim3(256), 0, stream,
                       hhiC, hloC, xphi, xplo,
                       WhiT + (size_t)i * 2 * 16384, WloT + (size_t)i * 2 * 16384,
                       b_hid + (size_t)i * 256, b_hid + (size_t)i * 256 + 128,
                       hfN, hhiN, hloN);
    _Float16* tf = hfC; hfC = hfN; hfN = tf;
    unsigned short* th = hhiC; hhiC = hhiN; hhiN = th;
    unsigned short* tl = hloC; hloC = hloN; hloN = tl;
  }

  // output layer: 128 -> 2
  hipLaunchKernelGGL(k_spmm128, dim3((NN + 3) / 4), dim3(256), 0, stream,
                     hfC, rowptr, col, dinv, xphi, xplo);
  hipLaunchKernelGGL(k_out, dim3((NN + 3) / 4), dim3(256), 0, stream,
                     hfC, xphi, xplo, W_out, b_out, out);
}